// Round 4
// baseline (456.632 us; speedup 1.0000x reference)
//
#include <hip/hip_runtime.h>

typedef unsigned long long u64;
typedef unsigned int u32;

#define R_TOT 159882
#define POST 1000
#define IMG_SZ 800.0f
#define NMS_TH 0.7f
#define BBOX_CLIP 4.135166556742356f
#define SIDE_CAP 4096

__device__ __forceinline__ float fadd_(float a, float b){ return __fadd_rn(a,b); }
__device__ __forceinline__ float fsub_(float a, float b){ return __fsub_rn(a,b); }
__device__ __forceinline__ float fmul_(float a, float b){ return __fmul_rn(a,b); }

__device__ __forceinline__ int level_of(int r){
  return r < 120000 ? 0 : r < 150000 ? 1 : r < 157500 ? 2 : r < 159375 ? 3 : 4;
}
__device__ __forceinline__ int lvl_len(int l){ const int L[5]={120000,30000,7500,1875,507}; return L[l]; }
__device__ __forceinline__ int lvl_off(int l){ const int L[5]={0,120000,150000,157500,159375}; return L[l]; }
__device__ __forceinline__ int lvl_k(int l){ const int L[5]={1000,1000,1000,1000,507}; return L[l]; }

__device__ __forceinline__ u32 mono_(u32 u){ return (u & 0x80000000u) ? ~u : (u | 0x80000000u); }

// ---------- 0. zero the global histograms ----------
__global__ void k_zero(int* hist){
  int t = blockIdx.x * blockDim.x + threadIdx.x;
  if (t < 10*4096) hist[t] = 0;
}

// ---------- 1. 12-bit histogram per (img,lvl), level sliced across 8 blocks ----------
__global__ __launch_bounds__(256) void k_hist(const float* __restrict__ obj, int* hist){
  int g = blockIdx.x >> 3, sl = blockIdx.x & 7;
  int img = g/5, lvl = g%5;
  int n = lvl_len(lvl), s0 = lvl_off(lvl);
  int lo = (int)((long long)n * sl / 8), hiS = (int)((long long)n * (sl+1) / 8);
  const float* p = obj + img*R_TOT + s0;
  for (int e = lo + threadIdx.x; e < hiS; e += 256){
    u32 mu = mono_(__float_as_uint(p[e]));
    atomicAdd(&hist[g*4096 + (int)((~mu) >> 20)], 1);
  }
}

// ---------- 2. find bin of the k-th smallest key per g ----------
__global__ __launch_bounds__(256) void k_pick(const int* __restrict__ hist,
                                              int* bstarg, int* remg, int* cntg, int* cnt2){
  int g = blockIdx.x, lvl = g % 5, k = lvl_k(lvl);
  int tid = threadIdx.x, lane = tid & 63, wid = tid >> 6;
  __shared__ int wsum[4];
  int base = g*4096 + tid*16;
  int part = 0;
  #pragma unroll
  for (int q = 0; q < 16; q++) part += hist[base + q];
  int x = part;
  for (int d = 1; d < 64; d <<= 1){ int y = __shfl_up(x, d); if (lane >= d) x += y; }
  if (lane == 63) wsum[wid] = x;
  __syncthreads();
  int add = 0;
  for (int w = 0; w < wid; w++) add += wsum[w];
  int incl = x + add, excl = incl - part;
  if (excl < k && k <= incl){
    int cum = excl;
    for (int q = 0; q < 16; q++){
      int hb = hist[base + q];
      if (cum + hb >= k){ bstarg[g] = tid*16 + q; remg[g] = k - cum; break; }
      cum += hb;
    }
  }
  if (tid == 0){ cntg[g] = 0; cnt2[g] = 0; }
}

// ---------- 3. gather: bin<b* -> glist, bin==b* -> side ----------
__global__ void k_gather(const float* __restrict__ obj, const int* __restrict__ bstarg,
                         int* cntg, int* cnt2, u64* glist, u64* side){
  int t = blockIdx.x * blockDim.x + threadIdx.x;
  if (t >= 2*R_TOT) return;
  int img = t / R_TOT, r = t - img * R_TOT;
  int lvl = level_of(r);
  int g = img*5 + lvl;
  u32 mu = mono_(__float_as_uint(obj[t]));
  u64 key56 = (((u64)(~mu)) << 24) | (u32)r;
  int bin = (int)(key56 >> 44);
  int bs = bstarg[g];
  if (bin < bs){
    int pos = atomicAdd(&cntg[g], 1);
    glist[g*1024 + pos] = key56;
  } else if (bin == bs){
    int pos = atomicAdd(&cnt2[g], 1);
    if (pos < SIDE_CAP) side[g*SIDE_CAP + pos] = key56;
  }
}

// ---------- 4. resolve side (rank < rem) + bitonic sort 1024 -> sidx ----------
__global__ __launch_bounds__(256) void k_sortL(const u64* __restrict__ glist,
                                               const u64* __restrict__ side,
                                               const int* __restrict__ cntg,
                                               const int* __restrict__ cnt2,
                                               const int* __restrict__ remg, u32* sidx){
  __shared__ u64 sh[1024];
  __shared__ u64 sideL[SIDE_CAP];
  __shared__ int scnt;
  int g = blockIdx.x, tid = threadIdx.x;
  int nb = cntg[g];
  int c2 = cnt2[g]; if (c2 > SIDE_CAP) c2 = SIDE_CAP;
  int rem = remg[g];
  for (int i = tid; i < 1024; i += 256) sh[i] = (i < nb) ? glist[g*1024 + i] : ~0ull;
  for (int e = tid; e < c2; e += 256) sideL[e] = side[g*SIDE_CAP + e];
  if (tid == 0) scnt = 0;
  __syncthreads();
  for (int e = tid; e < c2; e += 256){
    u64 kk = sideL[e];
    int rk = 0;
    for (int q = 0; q < c2; q++) rk += (sideL[q] < kk) ? 1 : 0;
    if (rk < rem){ int p = atomicAdd(&scnt, 1); sh[nb + p] = kk; }
  }
  __syncthreads();
  for (int k2 = 2; k2 <= 1024; k2 <<= 1){
    for (int j = k2 >> 1; j > 0; j >>= 1){
      __syncthreads();
      for (int i = tid; i < 1024; i += 256){
        int ixj = i ^ j;
        if (ixj > i){
          u64 a = sh[i], b = sh[ixj];
          bool up = (i & k2) == 0;
          if ((a > b) == up){ sh[i] = b; sh[ixj] = a; }
        }
      }
    }
  }
  __syncthreads();
  for (int r = tid; r < 1024; r += 256) sidx[g*1024 + r] = (u32)(sh[r] & 0xFFFFFFu);
}

// ---------- 5. decode + clip + valid + sigmoid + okey; fused valid-compaction (prep) ----------
__global__ __launch_bounds__(1024) void k_decode(const float* __restrict__ obj,
                                                 const float4* __restrict__ deltas,
                                                 const float4* __restrict__ anchors,
                                                 const u32* __restrict__ sidx,
                                                 float4* boxL, float* scoreL, u64* okeyL,
                                                 unsigned char* keptR,
                                                 float4* nbox, int* nrank, int* ncnt){
  __shared__ float4 lbox[1024];
  __shared__ int lval[1024];
  int g = blockIdx.x, r = threadIdx.x;
  int img = g / 5, lvl = g % 5, K = lvl_k(lvl);
  int t = g*1024 + r;
  keptR[t] = 0;
  if (r < K){
    int idx = (int)sidx[t];
    float4 a = anchors[idx];
    float4 d = deltas[img*R_TOT + idx];
    float o = obj[img*R_TOT + idx];
    float wa = fsub_(a.z, a.x), ha = fsub_(a.w, a.y);
    float cxa = fadd_(a.x, fmul_(0.5f, wa)), cya = fadd_(a.y, fmul_(0.5f, ha));
    float dw = fminf(d.z, BBOX_CLIP), dh = fminf(d.w, BBOX_CLIP);
    float cx = fadd_(fmul_(d.x, wa), cxa), cy = fadd_(fmul_(d.y, ha), cya);
    float w  = fmul_(expf(dw), wa),        h  = fmul_(expf(dh), ha);
    float x1 = fsub_(cx, fmul_(0.5f, w)), y1 = fsub_(cy, fmul_(0.5f, h));
    float x2 = fadd_(cx, fmul_(0.5f, w)), y2 = fadd_(cy, fmul_(0.5f, h));
    x1 = fminf(fmaxf(x1, 0.0f), IMG_SZ); y1 = fminf(fmaxf(y1, 0.0f), IMG_SZ);
    x2 = fminf(fmaxf(x2, 0.0f), IMG_SZ); y2 = fminf(fmaxf(y2, 0.0f), IMG_SZ);
    bool valid = (fsub_(x2, x1) >= 1e-3f) && (fsub_(y2, y1) >= 1e-3f);
    float e = expf(-o);
    float sig = __fdiv_rn(1.0f, fadd_(1.0f, e));
    float s = valid ? sig : -1.0f;
    u32 sb = __float_as_uint(s);
    u32 ms = (sb & 0x80000000u) ? ~sb : (sb | 0x80000000u);
    float4 b4 = make_float4(x1, y1, x2, y2);
    boxL[t] = b4;
    scoreL[t] = sig;
    okeyL[t] = (((u64)(~ms)) << 32) | (u32)(lvl*1000 + r);
    lbox[r] = b4;
    lval[r] = valid ? 1 : 0;
  } else {
    lval[r] = 0;
  }
  __syncthreads();
  if (r < 64){
    int lane = r, cnt = 0;
    float off = (float)lvl * 801.0f;
    for (int base = 0; base < K; base += 64){
      int r2 = base + lane;
      bool v = lval[r2] != 0;
      float4 b = lbox[r2];
      u64 mask = __ballot(v);
      int before = __popcll(mask & ((1ull << lane) - 1ull));
      if (v){
        int pos = cnt + before;
        nbox[g*1024 + pos] = make_float4(fadd_(b.x,off), fadd_(b.y,off), fadd_(b.z,off), fadd_(b.w,off));
        nrank[g*1024 + pos] = r2;
      }
      cnt += __popcll(mask);
    }
    if (lane == 0) ncnt[g] = cnt;
  }
}

// ---------- 6. transposed IoU bitmask: maskT[j][w] bit ii = (i=w*64+ii suppresses j, i<j) ----------
__global__ __launch_bounds__(64) void k_mask(const float4* __restrict__ nbox,
                                             const int* __restrict__ ncnt, u64* maskT){
  int g = blockIdx.x, tr = blockIdx.y, tw = blockIdx.z;
  if (tw > tr) return;
  int m = ncnt[g];
  if (tr*64 >= m) return;
  __shared__ float4 shb[64];
  int lane = threadIdx.x;
  if (tw*64 + lane < m) shb[lane] = nbox[g*1024 + tw*64 + lane];
  __syncthreads();
  int j = tr*64 + lane;
  if (j >= m) return;
  float4 a = nbox[g*1024 + j];
  float areaA = fmul_(fsub_(a.z,a.x), fsub_(a.w,a.y));
  int imax = m - tw*64; if (imax > 64) imax = 64;
  int cap = (tw == tr) ? (lane < imax ? lane : imax) : imax;   // enforce i < j
  u64 bits = 0;
  for (int ii = 0; ii < cap; ii++){
    float4 b = shb[ii];
    float ltx = fmaxf(a.x, b.x), lty = fmaxf(a.y, b.y);
    float rbx = fminf(a.z, b.z), rby = fminf(a.w, b.w);
    float wx = fmaxf(fsub_(rbx, ltx), 0.0f), wy = fmaxf(fsub_(rby, lty), 0.0f);
    float inter = fmul_(wx, wy);
    float areaB = fmul_(fsub_(b.z,b.x), fsub_(b.w,b.y));
    float den = fadd_(fsub_(fadd_(areaA, areaB), inter), 1e-9f);
    if (__fdiv_rn(inter, den) > NMS_TH) bits |= (1ull << ii);
  }
  maskT[(size_t)(g*1024 + j)*16 + tw] = bits;
}

// ---------- 7. greedy scan: register-resident rows, ballot-only serial chain ----------
__global__ __launch_bounds__(64) void k_scan(const u64* __restrict__ maskT,
                                             const int* __restrict__ ncnt,
                                             const int* __restrict__ nrank,
                                             unsigned char* keptR){
  int g = blockIdx.x, lane = threadIdx.x;
  int m = ncnt[g];
  __shared__ u64 K[16];
  if (lane < 16) K[lane] = 0;
  __syncthreads();
  int nch = (m + 63) >> 6;
  for (int c = 0; c < nch; c++){
    int row = c*64 + lane;
    u64 rT[16];
    if (row < m){
      const ulonglong2* p2 = (const ulonglong2*)(maskT + (size_t)(g*1024 + row)*16);
      #pragma unroll
      for (int q = 0; q < 8; q++){ ulonglong2 v = p2[q]; rT[2*q] = v.x; rT[2*q+1] = v.y; }
    } else {
      #pragma unroll
      for (int q = 0; q < 16; q++) rT[q] = 0;
    }
    int rnk = (row < m) ? nrank[g*1024 + row] : 0;
    u64 supp = 0;
    #pragma unroll
    for (int w = 0; w < 16; w++) supp |= rT[w] & K[w];   // K[w]=0 for w>=c (not yet written)
    bool alive = (row < m) && (supp == 0);
    u64 colbits = rT[c];
    u64 live = __ballot(alive);
    u64 kept = 0;
    while (live){
      int i = __builtin_ctzll(live);
      kept |= (1ull << i);
      if ((colbits >> i) & 1ull) alive = false;          // bit i of lane i is 0 (strict i<j)
      u64 below = (1ull << i) | ((1ull << i) - 1ull);
      live = __ballot(alive) & ~below;
    }
    if (row < m && ((kept >> lane) & 1ull)) keptR[g*1024 + rnk] = 1;
    __syncthreads();
    if (lane == 0) K[c] = kept;
    __syncthreads();
  }
}

// ---------- 8. compact kept per level, 8-run bitonic merge, output ----------
__global__ __launch_bounds__(1024) void k_merge_out(const unsigned char* __restrict__ keptR,
                                                    const u64* __restrict__ okeyL,
                                                    const float4* __restrict__ boxL,
                                                    const float* __restrict__ scoreL,
                                                    float* out){
  int img = blockIdx.x, tid = threadIdx.x, lane = tid & 63, wid = tid >> 6;
  __shared__ u64 S[8192];
  __shared__ int cl[8];
  for (int i = tid; i < 8192; i += 1024) S[i] = ~0ull;
  if (tid < 8) cl[tid] = 0;
  __syncthreads();
  if (wid < 5){
    int l = wid, g = img*5 + l;
    int cnt = 0;
    for (int base = 0; base < 1024; base += 64){
      int r = base + lane;
      bool kp = keptR[g*1024 + r] != 0;
      u64 mask = __ballot(kp);
      int before = __popcll(mask & ((1ull << lane) - 1ull));
      if (kp) S[l*1024 + cnt + before] = okeyL[g*1024 + r];
      cnt += __popcll(mask);
    }
    if (lane == 0) cl[l] = cnt;
  }
  __syncthreads();
  for (int w = 2048; w <= 8192; w <<= 1){
    for (int i = tid; i < 8192; i += 1024){
      int blk = i & ~(w-1), off = i & (w-1);
      if (off < (w >> 1)){
        int j = blk + (w-1) - off;
        u64 a = S[i], b = S[j];
        if (a > b){ S[i] = b; S[j] = a; }
      }
    }
    for (int j = w >> 2; j > 0; j >>= 1){
      __syncthreads();
      for (int i = tid; i < 8192; i += 1024){
        int ixj = i ^ j;
        if (ixj > i){
          u64 a = S[i], b = S[ixj];
          if (a > b){ S[i] = b; S[ixj] = a; }
        }
      }
    }
    __syncthreads();
  }
  int keptTotal = cl[0] + cl[1] + cl[2] + cl[3] + cl[4];
  int lim = keptTotal < POST ? keptTotal : POST;
  for (int t = tid; t < POST; t += 1024){
    float4 bo = make_float4(0,0,0,0);
    float sc = -1.0f;
    if (t < lim){
      u64 key = S[t];
      int pos = (int)(key & 0xFFFFFFFFull);
      int lvl = pos / 1000, r = pos - lvl*1000;
      int g = img*5 + lvl;
      bo = boxL[g*1024 + r];
      sc = scoreL[g*1024 + r];
    }
    out[img*POST*4 + t*4 + 0] = bo.x;
    out[img*POST*4 + t*4 + 1] = bo.y;
    out[img*POST*4 + t*4 + 2] = bo.z;
    out[img*POST*4 + t*4 + 3] = bo.w;
    out[2*POST*4 + img*POST + t] = sc;
  }
}

extern "C" void kernel_launch(void* const* d_in, const int* in_sizes, int n_in,
                              void* d_out, int out_size, void* d_ws, size_t ws_size,
                              hipStream_t stream){
  (void)in_sizes; (void)n_in; (void)out_size; (void)ws_size;
  const float*  obj     = (const float*)d_in[0];
  const float4* deltas  = (const float4*)d_in[1];
  const float4* anchors = (const float4*)d_in[2];
  float* out = (float*)d_out;
  char* ws = (char*)d_ws;
  int* hist    = (int*)(ws + 0);           // 10*4096 int  -> 163840
  int* bstarg  = (int*)(ws + 163840);      // 10 int       -> 164096
  int* remg    = (int*)(ws + 164096);      // 10 int       -> 164352
  int* cntg    = (int*)(ws + 164352);      // 10 int       -> 164608
  int* cnt2    = (int*)(ws + 164608);      // 10 int       -> 164864
  u64* glist   = (u64*)(ws + 164864);      // 10*1024 u64  -> 246784
  u64* side    = (u64*)(ws + 246784);      // 10*4096 u64  -> 574464
  u32* sidx    = (u32*)(ws + 574464);      // 10*1024 u32  -> 615424
  float4* boxL = (float4*)(ws + 615424);   // 10*1024 f4   -> 779264
  float* scoreL= (float*)(ws + 779264);    // 10*1024 f32  -> 820224
  u64* okeyL   = (u64*)(ws + 820224);      // 10*1024 u64  -> 902144
  float4* nbox = (float4*)(ws + 902144);   // 10*1024 f4   -> 1065984
  int* nrank   = (int*)(ws + 1065984);     // 10*1024 int  -> 1106944
  int* ncnt    = (int*)(ws + 1106944);     // 10 int (pad) -> 1107200
  unsigned char* keptR = (unsigned char*)(ws + 1107200); // 10*1024 -> 1117440
  u64* maskT   = (u64*)(ws + 1117440);     // 10*1024*16 u64 -> 2428160

  k_zero  <<<160, 256, 0, stream>>>(hist);
  k_hist  <<<80, 256, 0, stream>>>(obj, hist);
  k_pick  <<<10, 256, 0, stream>>>(hist, bstarg, remg, cntg, cnt2);
  k_gather<<<(2*R_TOT + 255)/256, 256, 0, stream>>>(obj, bstarg, cntg, cnt2, glist, side);
  k_sortL <<<10, 256, 0, stream>>>(glist, side, cntg, cnt2, remg, sidx);
  k_decode<<<10, 1024, 0, stream>>>(obj, deltas, anchors, sidx, boxL, scoreL, okeyL, keptR, nbox, nrank, ncnt);
  {
    dim3 gm(10, 16, 16);
    k_mask<<<gm, 64, 0, stream>>>(nbox, ncnt, maskT);
  }
  k_scan  <<<10, 64, 0, stream>>>(maskT, ncnt, nrank, keptR);
  k_merge_out<<<2, 1024, 0, stream>>>(keptR, okeyL, boxL, scoreL, out);
}

// Round 5
// 246.171 us; speedup vs baseline: 1.8549x; 1.8549x over previous
//
#include <hip/hip_runtime.h>

typedef unsigned long long u64;
typedef unsigned int u32;

#define R_TOT 159882
#define POST 1000
#define IMG_SZ 800.0f
#define NMS_TH 0.7f
#define BBOX_CLIP 4.135166556742356f
#define LCAP 2048

__device__ __forceinline__ float fadd_(float a, float b){ return __fadd_rn(a,b); }
__device__ __forceinline__ float fsub_(float a, float b){ return __fsub_rn(a,b); }
__device__ __forceinline__ float fmul_(float a, float b){ return __fmul_rn(a,b); }

__device__ __forceinline__ int lvl_len(int l){ const int L[5]={120000,30000,7500,1875,507}; return L[l]; }
__device__ __forceinline__ int lvl_off(int l){ const int L[5]={0,120000,150000,157500,159375}; return L[l]; }
__device__ __forceinline__ int lvl_k(int l){ const int L[5]={1000,1000,1000,1000,507}; return L[l]; }

__device__ __forceinline__ u32 mono_(u32 u){ return (u & 0x80000000u) ? ~u : (u | 0x80000000u); }

// ---------- 1. 12-bit histogram per (img,lvl): LDS-private, merged once ----------
__global__ __launch_bounds__(256) void k_hist(const float* __restrict__ obj, int* hist){
  int g = blockIdx.x, sl = blockIdx.y;
  int img = g/5, lvl = g%5;
  int n = lvl_len(lvl), s0 = lvl_off(lvl);
  __shared__ int lh[4096];
  int tid = threadIdx.x;
  for (int i = tid; i < 4096; i += 256) lh[i] = 0;
  __syncthreads();
  int lo = (int)((long long)n * sl / 16), hiS = (int)((long long)n * (sl+1) / 16);
  const float* p = obj + img*R_TOT + s0;
  #pragma unroll 4
  for (int e = lo + tid; e < hiS; e += 256){
    u32 mu = mono_(__float_as_uint(p[e]));
    atomicAdd(&lh[(~mu) >> 20], 1);
  }
  __syncthreads();
  for (int i = tid; i < 4096; i += 256)
    if (lh[i]) atomicAdd(&hist[g*4096 + i], lh[i]);
}

// ---------- 2. fused: pick bin + gather + rank-resolve + sort + decode + prep ----------
__global__ __launch_bounds__(1024) void k_sel(const float* __restrict__ obj,
                                              const float4* __restrict__ deltas,
                                              const float4* __restrict__ anchors,
                                              const int* __restrict__ hist,
                                              float4* boxL, float* scoreL, u64* okeyL,
                                              float4* nbox, int* nrank, int* ncnt){
  int g = blockIdx.x, img = g/5, lvl = g%5;
  int s0 = lvl_off(lvl), n = lvl_len(lvl), k = lvl_k(lvl);
  const float* p = obj + img*R_TOT + s0;
  __shared__ u64 Lbuf[LCAP];
  __shared__ u64 mainL[1024];
  __shared__ float4 lbox[1024];
  __shared__ unsigned char lval[1024];
  __shared__ int wsum[16];
  __shared__ int h16[16];
  __shared__ int sh_b, sh_rem, sh_nb, sh_c2, sh_sc;
  __shared__ u64 sh_thr;
  int tid = threadIdx.x, lane = tid & 63, wid = tid >> 6;
  // --- pick k-th bin from global hist ---
  const int* hg = hist + g*4096;
  int hh[4] = {hg[4*tid], hg[4*tid+1], hg[4*tid+2], hg[4*tid+3]};
  int part = hh[0] + hh[1] + hh[2] + hh[3];
  int x = part;
  for (int d = 1; d < 64; d <<= 1){ int y = __shfl_up(x, d); if (lane >= d) x += y; }
  if (lane == 63) wsum[wid] = x;
  if (tid == 0){ sh_nb = 0; sh_c2 = 0; sh_sc = 0; }
  mainL[tid] = ~0ull;
  __syncthreads();
  int add = 0;
  for (int w = 0; w < wid; w++) add += wsum[w];
  int incl = x + add, excl = incl - part;
  if (excl < k && k <= incl){
    int cum = excl;
    #pragma unroll
    for (int q = 0; q < 4; q++){
      if (cum + hh[q] >= k){ sh_b = 4*tid + q; sh_rem = k - cum; break; }
      cum += hh[q];
    }
  }
  __syncthreads();
  int bs = sh_b, rem = sh_rem;
  // --- single collect scan: bin<b* -> mainL, bin==b* -> Lbuf ---
  #pragma unroll 2
  for (int e = tid; e < n; e += 1024){
    u32 mu = mono_(__float_as_uint(p[e]));
    u64 key56 = (((u64)(~mu)) << 24) | (u32)(s0 + e);
    int bin = (int)(key56 >> 44);
    if (bin < bs){ int pos = atomicAdd(&sh_nb, 1); mainL[pos] = key56; }
    else if (bin == bs){ int pos = atomicAdd(&sh_c2, 1); if (pos < LCAP) Lbuf[pos] = key56; }
  }
  __syncthreads();
  int nb = sh_nb, c2 = sh_c2;
  if (c2 <= LCAP){
    // rank-select within the tie bin (uniform q -> LDS broadcast)
    for (int e = tid; e < c2; e += 1024){
      u64 kk = Lbuf[e];
      int rk = 0;
      for (int q = 0; q < c2; q++) rk += (Lbuf[q] < kk) ? 1 : 0;
      if (rk < rem){ int p2 = atomicAdd(&sh_sc, 1); mainL[nb + p2] = kk; }
    }
  } else {
    // fallback: 4-bit radix refine over global (never hit on bench data)
    if (tid == 0) sh_thr = ((u64)bs) << 44;
    __syncthreads();
    for (int shift = 40; shift >= 0; shift -= 4){
      if (tid < 16) h16[tid] = 0;
      __syncthreads();
      u64 pref = sh_thr;
      u64 himask = ~((1ull << (shift+4)) - 1ull);
      for (int e = tid; e < n; e += 1024){
        u32 mu = mono_(__float_as_uint(p[e]));
        u64 kk = (((u64)(~mu)) << 24) | (u32)(s0 + e);
        if ((kk & himask) == (pref & himask)) atomicAdd(&h16[(int)((kk >> shift) & 15)], 1);
      }
      __syncthreads();
      if (tid == 0){
        int r2 = sh_rem, cum = 0;
        for (int d = 0; d < 16; d++){
          int hb = h16[d];
          if (cum + hb >= r2){ sh_thr = pref | ((u64)d << shift); sh_rem = r2 - cum; break; }
          cum += hb;
        }
      }
      __syncthreads();
    }
    u64 thr = sh_thr;
    for (int e = tid; e < n; e += 1024){
      u32 mu = mono_(__float_as_uint(p[e]));
      u64 kk = (((u64)(~mu)) << 24) | (u32)(s0 + e);
      if ((int)(kk >> 44) == bs && kk <= thr){ int p2 = atomicAdd(&sh_sc, 1); mainL[nb + p2] = kk; }
    }
  }
  __syncthreads();
  // --- bitonic sort 1024 (55 stages) ---
  for (int k2 = 2; k2 <= 1024; k2 <<= 1){
    for (int j = k2 >> 1; j > 0; j >>= 1){
      __syncthreads();
      int i = tid, ixj = i ^ j;
      if (ixj > i){
        u64 a = mainL[i], b = mainL[ixj];
        bool up = (i & k2) == 0;
        if ((a > b) == up){ mainL[i] = b; mainL[ixj] = a; }
      }
    }
  }
  __syncthreads();
  // --- decode + clip + valid + sigmoid + okey ---
  int r = tid, t = g*1024 + r;
  if (r < k){
    int idx = (int)(mainL[r] & 0xFFFFFFu);
    float4 a = anchors[idx];
    float4 d = deltas[img*R_TOT + idx];
    float o = obj[img*R_TOT + idx];
    float wa = fsub_(a.z, a.x), ha = fsub_(a.w, a.y);
    float cxa = fadd_(a.x, fmul_(0.5f, wa)), cya = fadd_(a.y, fmul_(0.5f, ha));
    float dw = fminf(d.z, BBOX_CLIP), dh = fminf(d.w, BBOX_CLIP);
    float cx = fadd_(fmul_(d.x, wa), cxa), cy = fadd_(fmul_(d.y, ha), cya);
    float w  = fmul_(expf(dw), wa),        h  = fmul_(expf(dh), ha);
    float x1 = fsub_(cx, fmul_(0.5f, w)), y1 = fsub_(cy, fmul_(0.5f, h));
    float x2 = fadd_(cx, fmul_(0.5f, w)), y2 = fadd_(cy, fmul_(0.5f, h));
    x1 = fminf(fmaxf(x1, 0.0f), IMG_SZ); y1 = fminf(fmaxf(y1, 0.0f), IMG_SZ);
    x2 = fminf(fmaxf(x2, 0.0f), IMG_SZ); y2 = fminf(fmaxf(y2, 0.0f), IMG_SZ);
    bool valid = (fsub_(x2, x1) >= 1e-3f) && (fsub_(y2, y1) >= 1e-3f);
    float e = expf(-o);
    float sig = __fdiv_rn(1.0f, fadd_(1.0f, e));
    float s = valid ? sig : -1.0f;
    u32 sb = __float_as_uint(s);
    u32 ms = (sb & 0x80000000u) ? ~sb : (sb | 0x80000000u);
    float4 b4 = make_float4(x1, y1, x2, y2);
    boxL[t] = b4;
    scoreL[t] = sig;
    okeyL[t] = (((u64)(~ms)) << 32) | (u32)(lvl*1000 + r);
    lbox[r] = b4;
    lval[r] = valid ? 1 : 0;
  } else {
    lval[r] = 0;
  }
  __syncthreads();
  // --- valid-compaction (wave 0) with 801*lvl offset ---
  if (tid < 64){
    int cnt = 0;
    float off = (float)lvl * 801.0f;
    for (int base = 0; base < k; base += 64){
      int r2 = base + lane;
      bool v = (r2 < k) && lval[r2];
      float4 b = lbox[r2 < k ? r2 : 0];
      u64 mask = __ballot(v);
      int before = __popcll(mask & ((1ull << lane) - 1ull));
      if (v){
        int pos = cnt + before;
        nbox[g*1024 + pos] = make_float4(fadd_(b.x,off), fadd_(b.y,off), fadd_(b.z,off), fadd_(b.w,off));
        nrank[g*1024 + pos] = r2;
      }
      cnt += __popcll(mask);
    }
    if (lane == 0) ncnt[g] = cnt;
  }
}

// ---------- 3. transposed IoU bitmask ----------
__global__ __launch_bounds__(64) void k_mask(const float4* __restrict__ nbox,
                                             const int* __restrict__ ncnt, u64* maskT){
  int g = blockIdx.x, tr = blockIdx.y, tw = blockIdx.z;
  if (tw > tr) return;
  int m = ncnt[g];
  if (tr*64 >= m) return;
  __shared__ float4 shb[64];
  int lane = threadIdx.x;
  if (tw*64 + lane < m) shb[lane] = nbox[g*1024 + tw*64 + lane];
  __syncthreads();
  int j = tr*64 + lane;
  if (j >= m) return;
  float4 a = nbox[g*1024 + j];
  float areaA = fmul_(fsub_(a.z,a.x), fsub_(a.w,a.y));
  int imax = m - tw*64; if (imax > 64) imax = 64;
  int cap = (tw == tr) ? (lane < imax ? lane : imax) : imax;   // strict i < j
  u64 bits = 0;
  for (int ii = 0; ii < cap; ii++){
    float4 b = shb[ii];
    float ltx = fmaxf(a.x, b.x), lty = fmaxf(a.y, b.y);
    float rbx = fminf(a.z, b.z), rby = fminf(a.w, b.w);
    float wx = fmaxf(fsub_(rbx, ltx), 0.0f), wy = fmaxf(fsub_(rby, lty), 0.0f);
    float inter = fmul_(wx, wy);
    float areaB = fmul_(fsub_(b.z,b.x), fsub_(b.w,b.y));
    float den = fadd_(fsub_(fadd_(areaA, areaB), inter), 1e-9f);
    if (__fdiv_rn(inter, den) > NMS_TH) bits |= (1ull << ii);
  }
  maskT[(size_t)(g*1024 + j)*16 + tw] = bits;
}

__device__ __forceinline__ int lbound(const u64* a, int n, u64 key){
  int lo = 0, hi = n;
  while (lo < hi){ int mid = (lo + hi) >> 1; if (a[mid] < key) lo = mid + 1; else hi = mid; }
  return lo;
}

// ---------- 4. fused greedy scan (waves 0-4) + 5-way merge by rank + output ----------
__global__ __launch_bounds__(1024) void k_scanmerge(const u64* __restrict__ maskT,
                                                    const int* __restrict__ ncnt,
                                                    const int* __restrict__ nrank,
                                                    const u64* __restrict__ okeyL,
                                                    const float4* __restrict__ boxL,
                                                    const float* __restrict__ scoreL,
                                                    float* out){
  int img = blockIdx.x, tid = threadIdx.x, lane = tid & 63, wid = tid >> 6;
  __shared__ unsigned char keptF[5*1024];
  __shared__ u64 runs[5*1024];
  __shared__ u64 Kw[5*16];
  __shared__ int cl[5];
  for (int i = tid; i < 5*1024; i += 1024) keptF[i] = 0;
  if (tid < 80) Kw[tid] = 0;
  if (tid < 5) cl[tid] = 0;
  __syncthreads();
  // --- per-level greedy scan, one wave each (wave-local LDS, no block barriers) ---
  if (wid < 5){
    int l = wid, g = img*5 + l;
    int m = ncnt[g];
    int nch = (m + 63) >> 6;
    for (int c = 0; c < nch; c++){
      int row = c*64 + lane;
      u64 rT[16];
      if (row < m){
        const ulonglong2* p2 = (const ulonglong2*)(maskT + (size_t)(g*1024 + row)*16);
        #pragma unroll
        for (int q = 0; q < 8; q++){ ulonglong2 v = p2[q]; rT[2*q] = v.x; rT[2*q+1] = v.y; }
      } else {
        #pragma unroll
        for (int q = 0; q < 16; q++) rT[q] = 0;
      }
      int rnk = (row < m) ? nrank[g*1024 + row] : 0;
      u64 supp = 0;
      #pragma unroll
      for (int w = 0; w < 16; w++) supp |= rT[w] & Kw[l*16 + w];  // Kw=0 for w>=c
      bool alive = (row < m) && (supp == 0);
      u64 colbits = rT[c];
      u64 live = __ballot(alive);
      u64 kept = 0;
      while (live){
        int i = __builtin_ctzll(live);
        kept |= (1ull << i);
        if ((colbits >> i) & 1ull) alive = false;
        u64 below = (1ull << i) | ((1ull << i) - 1ull);
        live = __ballot(alive) & ~below;
      }
      if (row < m && ((kept >> lane) & 1ull)) keptF[l*1024 + rnk] = 1;
      if (lane == 0) Kw[l*16 + c] = kept;   // in-wave DS ordering suffices
    }
  }
  __syncthreads();
  // --- compact kept per level into sorted LDS runs (ascending key) ---
  if (wid < 5){
    int l = wid, g = img*5 + l;
    int cnt = 0;
    for (int base = 0; base < 1024; base += 64){
      int r = base + lane;
      bool kp = keptF[l*1024 + r] != 0;
      u64 mask = __ballot(kp);
      int before = __popcll(mask & ((1ull << lane) - 1ull));
      if (kp) runs[l*1024 + cnt + before] = okeyL[g*1024 + r];
      cnt += __popcll(mask);
    }
    if (lane == 0) cl[l] = cnt;
  }
  __syncthreads();
  // --- defaults ---
  for (int t = tid; t < POST; t += 1024){
    out[img*POST*4 + t*4 + 0] = 0.0f;
    out[img*POST*4 + t*4 + 1] = 0.0f;
    out[img*POST*4 + t*4 + 2] = 0.0f;
    out[img*POST*4 + t*4 + 3] = 0.0f;
    out[2*POST*4 + img*POST + t] = -1.0f;
  }
  __syncthreads();
  // --- scatter: global rank = own index + sum of lower_bounds in other runs ---
  for (int idx = tid; idx < 5*1024; idx += 1024){
    int l = idx >> 10, i = idx & 1023;
    if (i < cl[l]){
      u64 key = runs[l*1024 + i];
      int rank = i;
      #pragma unroll
      for (int l2 = 0; l2 < 5; l2++)
        if (l2 != l) rank += lbound(runs + l2*1024, cl[l2], key);
      if (rank < POST){
        int pos = (int)(key & 0xFFFFFFFFull);
        int lvl = pos / 1000, r = pos - lvl*1000;
        int gg = img*5 + lvl;
        float4 bo = boxL[gg*1024 + r];
        float sc = scoreL[gg*1024 + r];
        out[img*POST*4 + rank*4 + 0] = bo.x;
        out[img*POST*4 + rank*4 + 1] = bo.y;
        out[img*POST*4 + rank*4 + 2] = bo.z;
        out[img*POST*4 + rank*4 + 3] = bo.w;
        out[2*POST*4 + img*POST + rank] = sc;
      }
    }
  }
}

extern "C" void kernel_launch(void* const* d_in, const int* in_sizes, int n_in,
                              void* d_out, int out_size, void* d_ws, size_t ws_size,
                              hipStream_t stream){
  (void)in_sizes; (void)n_in; (void)out_size; (void)ws_size;
  const float*  obj     = (const float*)d_in[0];
  const float4* deltas  = (const float4*)d_in[1];
  const float4* anchors = (const float4*)d_in[2];
  float* out = (float*)d_out;
  char* ws = (char*)d_ws;
  int* hist    = (int*)(ws + 0);           // 10*4096 int   -> 163840
  float4* boxL = (float4*)(ws + 163840);   // 10*1024 f4    -> 327680
  float* scoreL= (float*)(ws + 327680);    // 10*1024 f32   -> 368640
  u64* okeyL   = (u64*)(ws + 368640);      // 10*1024 u64   -> 450560
  float4* nbox = (float4*)(ws + 450560);   // 10*1024 f4    -> 614400
  int* nrank   = (int*)(ws + 614400);      // 10*1024 int   -> 655360
  int* ncnt    = (int*)(ws + 655360);      // 10 int (pad)  -> 655616
  u64* maskT   = (u64*)(ws + 655616);      // 10*1024*16 u64 -> 1966336

  hipMemsetAsync(hist, 0, 10*4096*sizeof(int), stream);
  {
    dim3 gh(10, 16);
    k_hist<<<gh, 256, 0, stream>>>(obj, hist);
  }
  k_sel  <<<10, 1024, 0, stream>>>(obj, deltas, anchors, hist, boxL, scoreL, okeyL, nbox, nrank, ncnt);
  {
    dim3 gm(10, 16, 16);
    k_mask<<<gm, 64, 0, stream>>>(nbox, ncnt, maskT);
  }
  k_scanmerge<<<2, 1024, 0, stream>>>(maskT, ncnt, nrank, okeyL, boxL, scoreL, out);
}